// Round 1
// baseline (608.614 us; speedup 1.0000x reference)
//
#include <hip/hip_runtime.h>

constexpr int Dz = 96, Hy = 160, Wx = 160;
constexpr int NVOX = Dz * Hy * Wx;

__global__ __launch_bounds__(256) void st_fused_kernel(
    const float* __restrict__ src,
    const float* __restrict__ flows,
    const float* __restrict__ rfp,
    float* __restrict__ out)
{
    int idx = blockIdx.x * 256 + threadIdx.x;
    if (idx >= NVOX) return;
    const float rf = *rfp;

    int w = idx % Wx;
    int t = idx / Wx;
    int h = t % Hy;
    int d = t / Hy;

    // ---- Stage 1: sample the 3 flow fields (border mode) ----
    // Axis swap per reference: grid channel 0 (d-based) -> x (W axis),
    // channel 1 (h) -> y (H axis), channel 2 (w) -> z (D axis).
    float x = ((2.0f * ((float)d / (float)Dz) - 1.0f) + 1.0f) * 0.5f * (float)(Wx - 1);
    float y = ((2.0f * ((float)h / (float)Hy) - 1.0f) + 1.0f) * 0.5f * (float)(Hy - 1);
    float z = ((2.0f * ((float)w / (float)Wx) - 1.0f) + 1.0f) * 0.5f * (float)(Dz - 1);
    // border clamp
    x = fminf(fmaxf(x, 0.0f), (float)(Wx - 1));
    y = fminf(fmaxf(y, 0.0f), (float)(Hy - 1));
    z = fminf(fmaxf(z, 0.0f), (float)(Dz - 1));

    float x0f = floorf(x), y0f = floorf(y), z0f = floorf(z);
    float fx = x - x0f, fy = y - y0f, fz = z - z0f;
    int x0 = (int)x0f, y0 = (int)y0f, z0 = (int)z0f;
    int x1 = min(x0 + 1, Wx - 1);
    int y1 = min(y0 + 1, Hy - 1);
    int z1 = min(z0 + 1, Dz - 1);

    float w000 = (1.0f - fz) * (1.0f - fy) * (1.0f - fx);
    float w001 = (1.0f - fz) * (1.0f - fy) * fx;
    float w010 = (1.0f - fz) * fy * (1.0f - fx);
    float w011 = (1.0f - fz) * fy * fx;
    float w100 = fz * (1.0f - fy) * (1.0f - fx);
    float w101 = fz * (1.0f - fy) * fx;
    float w110 = fz * fy * (1.0f - fx);
    float w111 = fz * fy * fx;

    int o000 = (z0 * Hy + y0) * Wx + x0;
    int o001 = (z0 * Hy + y0) * Wx + x1;
    int o010 = (z0 * Hy + y1) * Wx + x0;
    int o011 = (z0 * Hy + y1) * Wx + x1;
    int o100 = (z1 * Hy + y0) * Wx + x0;
    int o101 = (z1 * Hy + y0) * Wx + x1;
    int o110 = (z1 * Hy + y1) * Wx + x0;
    int o111 = (z1 * Hy + y1) * Wx + x1;

    float acc0 = 0.0f, acc1 = 0.0f, acc2 = 0.0f;
#pragma unroll
    for (int p = 0; p < 9; ++p) {
        const float* f = flows + (size_t)p * NVOX;
        float v = w000 * f[o000] + w001 * f[o001] + w010 * f[o010] + w011 * f[o011]
                + w100 * f[o100] + w101 * f[o101] + w110 * f[o110] + w111 * f[o111];
        int c = p % 3;
        if (c == 0) acc0 += v;
        else if (c == 1) acc1 += v;
        else acc2 += v;
    }

    // ---- Stage 2: sample src (zeros mode) at displaced coords ----
    float f0 = (float)d + acc0 * rf;   // channel 0 -> x (W axis)
    float f1 = (float)h + acc1 * rf;   // channel 1 -> y (H axis)
    float f2 = (float)w + acc2 * rf;   // channel 2 -> z (D axis)

    float xs = (2.0f * (f0 / (float)(Dz - 1) - 0.5f) + 1.0f) * 0.5f * (float)(Wx - 1);
    float ys = (2.0f * (f1 / (float)(Hy - 1) - 0.5f) + 1.0f) * 0.5f * (float)(Hy - 1);
    float zs = (2.0f * (f2 / (float)(Wx - 1) - 0.5f) + 1.0f) * 0.5f * (float)(Dz - 1);

    float xs0f = floorf(xs), ys0f = floorf(ys), zs0f = floorf(zs);
    float gx = xs - xs0f, gy = ys - ys0f, gz = zs - zs0f;
    int xi0 = (int)xs0f, yi0 = (int)ys0f, zi0 = (int)zs0f;
    int xi1 = xi0 + 1, yi1 = yi0 + 1, zi1 = zi0 + 1;

    auto samp = [&](int zi, int yi, int xi, float wt) -> float {
        bool valid = ((unsigned)zi < (unsigned)Dz)
                   & ((unsigned)yi < (unsigned)Hy)
                   & ((unsigned)xi < (unsigned)Wx);
        int zc = min(max(zi, 0), Dz - 1);
        int yc = min(max(yi, 0), Hy - 1);
        int xc = min(max(xi, 0), Wx - 1);
        float v = src[(zc * Hy + yc) * Wx + xc];
        return valid ? wt * v : 0.0f;
    };

    float r = samp(zi0, yi0, xi0, (1.0f - gz) * (1.0f - gy) * (1.0f - gx))
            + samp(zi0, yi0, xi1, (1.0f - gz) * (1.0f - gy) * gx)
            + samp(zi0, yi1, xi0, (1.0f - gz) * gy * (1.0f - gx))
            + samp(zi0, yi1, xi1, (1.0f - gz) * gy * gx)
            + samp(zi1, yi0, xi0, gz * (1.0f - gy) * (1.0f - gx))
            + samp(zi1, yi0, xi1, gz * (1.0f - gy) * gx)
            + samp(zi1, yi1, xi0, gz * gy * (1.0f - gx))
            + samp(zi1, yi1, xi1, gz * gy * gx);

    out[idx] = r;
}

extern "C" void kernel_launch(void* const* d_in, const int* in_sizes, int n_in,
                              void* d_out, int out_size, void* d_ws, size_t ws_size,
                              hipStream_t stream) {
    const float* src   = (const float*)d_in[0];
    const float* flows = (const float*)d_in[1];
    const float* rfp   = (const float*)d_in[2];
    float* out = (float*)d_out;

    int nblocks = (NVOX + 255) / 256;
    st_fused_kernel<<<nblocks, 256, 0, stream>>>(src, flows, rfp, out);
}

// Round 2
// 65.043 us; speedup vs baseline: 9.3571x; 9.3571x over previous
//
#include <hip/hip_runtime.h>

constexpr int Dz = 96, Hy = 160, Wx = 160;
constexpr int NVOX = Dz * Hy * Wx;

// Tile: 32 d  x  32 w  x  1 h per block. Lanes vary d (fast axis of both
// gathers); LDS transpose so global writes are w-contiguous.
__global__ __launch_bounds__(256) void st_fused_kernel(
    const float* __restrict__ src,
    const float* __restrict__ flows,
    const float* __restrict__ rfp,
    float* __restrict__ out)
{
    __shared__ float tile[32][33];  // +1 pad: conflict-free column writes
    const int t  = threadIdx.x;
    const int w0 = blockIdx.x * 32;
    const int d0 = blockIdx.y * 32;
    const int h  = blockIdx.z;
    const float rf = *rfp;

    const int dl = t & 31;
    const int d  = d0 + dl;

    // Stage-1 sample coords (axis-swapped, separable). All in-range by
    // construction: x<=157.34, y<=158.01, z<=94.41 -> no border clamps needed.
    const float x   = (float)d * (159.0f / 96.0f);
    const int   x0i = (int)x;
    const float fx  = x - (float)x0i;
    const float y   = (float)h * (159.0f / 160.0f);
    const int   y0i = (int)y;
    const float fy  = y - (float)y0i;

    const float wx0 = 1.0f - fx, wx1 = fx;
    const float wy0 = 1.0f - fy, wy1 = fy;

    const int wl0 = t >> 5;

#pragma unroll
    for (int it = 0; it < 4; ++it) {
        const int wl = wl0 + 8 * it;
        const int w  = w0 + wl;

        const float z   = (float)w * (95.0f / 160.0f);
        const int   z0i = (int)z;
        const float fz  = z - (float)z0i;
        const float wz0 = 1.0f - fz, wz1 = fz;

        // Row bases for the 4 (z,y) corners; x0/x0+1 are adjacent in memory.
        const int r00 = (z0i * Hy + y0i) * Wx + x0i;  // z0,y0
        const int r01 = r00 + Wx;                     // z0,y1
        const int r10 = r00 + Hy * Wx;                // z1,y0
        const int r11 = r10 + Wx;                     // z1,y1

        float acc0 = 0.f, acc1 = 0.f, acc2 = 0.f;
#pragma unroll
        for (int p = 0; p < 9; ++p) {
            const float* f = flows + (size_t)p * NVOX;
            float v00 = f[r00] * wx0 + f[r00 + 1] * wx1;
            float v01 = f[r01] * wx0 + f[r01 + 1] * wx1;
            float v10 = f[r10] * wx0 + f[r10 + 1] * wx1;
            float v11 = f[r11] * wx0 + f[r11 + 1] * wx1;
            float v = wz0 * (wy0 * v00 + wy1 * v01) + wz1 * (wy0 * v10 + wy1 * v11);
            int c = p % 3;
            if (c == 0) acc0 += v;
            else if (c == 1) acc1 += v;
            else acc2 += v;
        }

        // Stage 2: sample src (zeros mode) at displaced coords.
        const float f0 = (float)d + acc0 * rf;  // -> x axis of src
        const float f1 = (float)h + acc1 * rf;  // -> y axis
        const float f2 = (float)w + acc2 * rf;  // -> z axis

        const float xs = f0 * (159.0f / 95.0f);
        const float ys = f1;                    // (Hy-1)/(Hy-1) == 1
        const float zs = f2 * (95.0f / 159.0f);

        const float xs0f = floorf(xs), ys0f = floorf(ys), zs0f = floorf(zs);
        const float gx = xs - xs0f, gy = ys - ys0f, gz = zs - zs0f;
        const int xi0 = (int)xs0f, yi0 = (int)ys0f, zi0 = (int)zs0f;
        const int xi1 = xi0 + 1, yi1 = yi0 + 1, zi1 = zi0 + 1;

        auto samp = [&](int zi, int yi, int xi, float wt) -> float {
            bool valid = ((unsigned)zi < (unsigned)Dz)
                       & ((unsigned)yi < (unsigned)Hy)
                       & ((unsigned)xi < (unsigned)Wx);
            int zc = min(max(zi, 0), Dz - 1);
            int yc = min(max(yi, 0), Hy - 1);
            int xc = min(max(xi, 0), Wx - 1);
            float v = src[(zc * Hy + yc) * Wx + xc];
            return valid ? wt * v : 0.0f;
        };

        float r = samp(zi0, yi0, xi0, (1.0f - gz) * (1.0f - gy) * (1.0f - gx))
                + samp(zi0, yi0, xi1, (1.0f - gz) * (1.0f - gy) * gx)
                + samp(zi0, yi1, xi0, (1.0f - gz) * gy * (1.0f - gx))
                + samp(zi0, yi1, xi1, (1.0f - gz) * gy * gx)
                + samp(zi1, yi0, xi0, gz * (1.0f - gy) * (1.0f - gx))
                + samp(zi1, yi0, xi1, gz * (1.0f - gy) * gx)
                + samp(zi1, yi1, xi0, gz * gy * (1.0f - gx))
                + samp(zi1, yi1, xi1, gz * gy * gx);

        tile[dl][wl] = r;
    }

    __syncthreads();

    // Write phase: lanes vary w -> coalesced stores.
#pragma unroll
    for (int it = 0; it < 4; ++it) {
        const int dloc = (t >> 5) + 8 * it;
        const int wl   = t & 31;
        out[((d0 + dloc) * Hy + h) * Wx + (w0 + wl)] = tile[dloc][wl];
    }
}

extern "C" void kernel_launch(void* const* d_in, const int* in_sizes, int n_in,
                              void* d_out, int out_size, void* d_ws, size_t ws_size,
                              hipStream_t stream) {
    const float* src   = (const float*)d_in[0];
    const float* flows = (const float*)d_in[1];
    const float* rfp   = (const float*)d_in[2];
    float* out = (float*)d_out;

    dim3 grid(Wx / 32, Dz / 32, Hy);  // (5, 3, 160)
    st_fused_kernel<<<grid, 256, 0, stream>>>(src, flows, rfp, out);
}